// Round 1
// baseline (1786.217 us; speedup 1.0000x reference)
//
#include <hip/hip_runtime.h>

// ---- problem constants ----
#define L_LAYERS 6
#define HEADS    8
#define DMODEL   512
#define DHEAD    64
#define SEQ      300
#define BATCH    64
#define DFFN     2048
#define BN_ROWS  (BATCH*SEQ)   // 19200 = 150 * 128 exactly
#define NPAD     320           // SEQ padded to 20*16

typedef __bf16 bf16_t;
typedef bf16_t bf16x8 __attribute__((ext_vector_type(8)));
typedef bf16_t bf16x4 __attribute__((ext_vector_type(4)));
typedef float  f32x4  __attribute__((ext_vector_type(4)));

// async global->LDS, 16B per lane. LDS dest must be linear in lane order.
#define GLOAD16(gp, lp) __builtin_amdgcn_global_load_lds( \
    (__attribute__((address_space(1))) void*)(gp),        \
    (__attribute__((address_space(3))) void*)(lp), 16, 0, 0)

// ---------------- weight transpose + bf16 convert ----------------
// generic: w [L][K][Nc] f32 row-major -> o [L][Nc][K] bf16
__global__ __launch_bounds__(256) void transpose_w8(const float* __restrict__ w,
                                                    bf16_t* __restrict__ o,
                                                    int K, int Nc)
{
    int idx = blockIdx.x * 256 + threadIdx.x;   // over L*K/8*Nc
    int n   = idx % Nc;
    int r   = idx / Nc;
    int k8  = (r % (K / 8)) * 8;
    int l   = r / (K / 8);
    const float* wp = w + (size_t)l * K * Nc + (size_t)k8 * Nc + n;
    bf16x8 t;
#pragma unroll
    for (int j = 0; j < 8; ++j) t[j] = (bf16_t)wp[(size_t)j * Nc];
    *(bf16x8*)(o + (size_t)l * K * Nc + (size_t)n * K + k8) = t;
}

// Wk [L][H][D][DH] f32 -> o [L][h*64+e][d] bf16  (fold heads into 512x512^T)
__global__ __launch_bounds__(256) void transpose_wk8(const float* __restrict__ wk,
                                                     bf16_t* __restrict__ o)
{
    int idx = blockIdx.x * 256 + threadIdx.x;   // over L*H*(D/8)*DH
    int e  = idx % DHEAD;
    int r  = idx / DHEAD;
    int d8 = (r % (DMODEL / 8)) * 8;
    r      = r / (DMODEL / 8);
    int h  = r % HEADS;
    int l  = r / HEADS;
    const float* wp = wk + (((size_t)(l * HEADS + h) * DMODEL + d8) * DHEAD + e);
    bf16x8 t;
#pragma unroll
    for (int j = 0; j < 8; ++j) t[j] = (bf16_t)wp[(size_t)j * DHEAD];
    *(bf16x8*)(o + (size_t)l * DMODEL * DMODEL + (size_t)(h * DHEAD + e) * DMODEL + d8) = t;
}

// ---------------- embedding ----------------
__global__ __launch_bounds__(128) void embed_k(const int* __restrict__ tok,
                                               const float* __restrict__ emb,
                                               const float* __restrict__ pos,
                                               bf16_t* __restrict__ xb)
{
    int row = blockIdx.x;            // 0..BN_ROWS-1
    int n   = row % SEQ;
    int tkn = tok[row];
    int c   = threadIdx.x * 4;
    float4 e = *(const float4*)(emb + (size_t)tkn * DMODEL + c);
    float4 p = *(const float4*)(pos + (size_t)n * DMODEL + c);
    bf16x4 o;
    o[0] = (bf16_t)(e.x + p.x); o[1] = (bf16_t)(e.y + p.y);
    o[2] = (bf16_t)(e.z + p.z); o[3] = (bf16_t)(e.w + p.w);
    *(bf16x4*)(xb + (size_t)row * DMODEL + c) = o;
}

// ---------------- GEMM: C = A[M,K] @ B (given as BT[N,K]) + epilogue ----------------
// EPI: 0 = none (bf16 out), 1 = +residual (f32 out), 2 = +bias,relu (bf16 out), 3 = +bias+residual (f32 out)
template <int EPI, typename OUT_T>
__global__ __launch_bounds__(256) void gemm_bt(const bf16_t* __restrict__ A,
                                               const bf16_t* __restrict__ BT,
                                               OUT_T* __restrict__ C,
                                               const float* __restrict__ bias,
                                               const bf16_t* __restrict__ resid,
                                               int M, int K, int Nc, int tiles_n)
{
    __shared__ bf16_t As[128 * 64];
    __shared__ bf16_t Bs[128 * 64];
    const int t    = threadIdx.x;
    const int tm   = blockIdx.x / tiles_n;
    const int tn   = blockIdx.x % tiles_n;
    const int lane = t & 63, wid = t >> 6;
    const int wr   = wid >> 1, wc = wid & 1;     // 2x2 waves, 64x64 each
    const int fr   = lane & 15, fq = lane >> 4;

    const f32x4 FZ = {0.f, 0.f, 0.f, 0.f};
    f32x4 acc[4][4];
#pragma unroll
    for (int m = 0; m < 4; ++m)
#pragma unroll
        for (int n = 0; n < 4; ++n) acc[m][n] = FZ;

    const bf16_t* Ab = A  + (size_t)tm * 128 * K;
    const bf16_t* Bb = BT + (size_t)tn * 128 * K;

    for (int k0 = 0; k0 < K; k0 += 64) {
        // stage 128x64 A and BT tiles; LDS linear, source pre-swizzled (XOR on 8-elem groups)
#pragma unroll
        for (int i = 0; i < 4; ++i) {
            int idx8 = (i * 256 + t) * 8;                 // element index, 8-aligned
            int row  = idx8 >> 6;
            int colg = (idx8 & 63) ^ ((row & 7) << 3);    // logical col for this storage slot
            GLOAD16(Ab + (size_t)row * K + k0 + colg, As + idx8);
            GLOAD16(Bb + (size_t)row * K + k0 + colg, Bs + idx8);
        }
        __syncthreads();
#pragma unroll
        for (int kk = 0; kk < 2; ++kk) {
            bf16x8 af[4], bfr[4];
#pragma unroll
            for (int m = 0; m < 4; ++m) {
                int row = wr * 64 + m * 16 + fr;
                af[m] = *(const bf16x8*)(As + row * 64 + ((kk * 32 + fq * 8) ^ ((row & 7) << 3)));
            }
#pragma unroll
            for (int n = 0; n < 4; ++n) {
                int row = wc * 64 + n * 16 + fr;
                bfr[n] = *(const bf16x8*)(Bs + row * 64 + ((kk * 32 + fq * 8) ^ ((row & 7) << 3)));
            }
#pragma unroll
            for (int m = 0; m < 4; ++m)
#pragma unroll
                for (int n = 0; n < 4; ++n)
                    acc[m][n] = __builtin_amdgcn_mfma_f32_16x16x32_bf16(af[m], bfr[n], acc[m][n], 0, 0, 0);
        }
        __syncthreads();
    }

    // epilogue: C layout col=lane&15, row=(lane>>4)*4+r
#pragma unroll
    for (int m = 0; m < 4; ++m) {
#pragma unroll
        for (int n = 0; n < 4; ++n) {
            int colg = tn * 128 + wc * 64 + n * 16 + fr;
            float bv = (EPI == 2 || EPI == 3) ? bias[colg] : 0.f;
#pragma unroll
            for (int r = 0; r < 4; ++r) {
                int rowg = tm * 128 + wr * 64 + m * 16 + fq * 4 + r;
                float v = acc[m][n][r] + bv;
                if (EPI == 2) v = fmaxf(v, 0.f);
                if (EPI == 1 || EPI == 3) v += (float)resid[(size_t)rowg * Nc + colg];
                C[(size_t)rowg * Nc + colg] = (OUT_T)v;
            }
        }
    }
}

// ---------------- fused attention for one (b,h); exploits Q=K=V ----------------
__global__ __launch_bounds__(256) void attn_k(const bf16_t* __restrict__ kin,
                                              bf16_t* __restrict__ out)
{
    __shared__ bf16_t Kl[NPAD * 64];       // [key][dh]   swizzled
    __shared__ bf16_t KT[64 * NPAD];       // [dh][key]   swizzled
    __shared__ bf16_t Pl[4 * 16 * NPAD];   // per-wave P  swizzled

    const int bh = blockIdx.x;
    const int b  = bh >> 3, h = bh & 7;
    const bf16_t* kbase = kin + (size_t)b * SEQ * DMODEL + h * DHEAD;
    const int t  = threadIdx.x;
    const int rr = t >> 3;
    const int cg = (t & 7) * 8;

    // load K tile (zero-pad rows >= SEQ); build both layouts
    for (int pass = 0; pass < NPAD / 32; ++pass) {
        int row = pass * 32 + rr;
        bf16x8 v;
        if (row < SEQ) v = *(const bf16x8*)(kbase + (size_t)row * DMODEL + cg);
        else {
#pragma unroll
            for (int j = 0; j < 8; ++j) v[j] = (bf16_t)0.f;
        }
        *(bf16x8*)(Kl + row * 64 + (cg ^ ((row & 7) << 3))) = v;
#pragma unroll
        for (int j = 0; j < 8; ++j) {
            int col = cg + j;   // dh index = KT row
            KT[col * NPAD + (row ^ ((col & 7) << 3))] = v[j];
        }
    }
    __syncthreads();

    const int lane = t & 63, w = t >> 6;
    const int fr = lane & 15, fq = lane >> 4;
    const float scale = 0.044194173824159216f;   // 1/sqrt(512) (module's D, not DH)
    const f32x4 FZ = {0.f, 0.f, 0.f, 0.f};

    for (int i = 0; i < 5; ++i) {
        int qt = w * 5 + i;                       // 20 q-tiles over 4 waves
        // S = Q K^T  (Q rows come from the same K tile)
        f32x4 s[20];
#pragma unroll
        for (int ct = 0; ct < 20; ++ct) s[ct] = FZ;
#pragma unroll
        for (int kk = 0; kk < 2; ++kk) {
            int qrow = qt * 16 + fr;
            bf16x8 aq = *(const bf16x8*)(Kl + qrow * 64 + ((kk * 32 + fq * 8) ^ ((qrow & 7) << 3)));
#pragma unroll
            for (int ct = 0; ct < 20; ++ct) {
                int krow = ct * 16 + fr;
                bf16x8 bk = *(const bf16x8*)(Kl + krow * 64 + ((kk * 32 + fq * 8) ^ ((krow & 7) << 3)));
                s[ct] = __builtin_amdgcn_mfma_f32_16x16x32_bf16(aq, bk, s[ct], 0, 0, 0);
            }
        }
        // softmax rows fq*4+r; row data spread over 16 lanes (col = ct*16 + fr)
#pragma unroll
        for (int r = 0; r < 4; ++r) {
            float mx = -1e30f;
#pragma unroll
            for (int ct = 0; ct < 20; ++ct) {
                float v = s[ct][r] * scale;
                if (ct * 16 + fr < SEQ) mx = fmaxf(mx, v);
            }
            mx = fmaxf(mx, __shfl_xor(mx, 1));
            mx = fmaxf(mx, __shfl_xor(mx, 2));
            mx = fmaxf(mx, __shfl_xor(mx, 4));
            mx = fmaxf(mx, __shfl_xor(mx, 8));
            float p[20];
            float sm = 0.f;
#pragma unroll
            for (int ct = 0; ct < 20; ++ct) {
                float v = (ct * 16 + fr < SEQ) ? __expf(s[ct][r] * scale - mx) : 0.f;
                p[ct] = v; sm += v;
            }
            sm += __shfl_xor(sm, 1); sm += __shfl_xor(sm, 2);
            sm += __shfl_xor(sm, 4); sm += __shfl_xor(sm, 8);
            float rinv = 1.f / sm;
            int pr = fq * 4 + r;
#pragma unroll
            for (int ct = 0; ct < 20; ++ct) {
                int col = ct * 16 + fr;
                Pl[(w * 16 + pr) * NPAD + (col ^ ((pr & 7) << 3))] = (bf16_t)(p[ct] * rinv);
            }
        }
        // O = P @ K  (B operand from transposed copy)
#pragma unroll
        for (int n = 0; n < 4; ++n) {
            f32x4 oacc = FZ;
#pragma unroll
            for (int kk = 0; kk < 10; ++kk) {
                bf16x8 ap = *(const bf16x8*)(Pl + (w * 16 + fr) * NPAD + ((kk * 32 + fq * 8) ^ ((fr & 7) << 3)));
                int dr = n * 16 + fr;
                bf16x8 bv = *(const bf16x8*)(KT + dr * NPAD + ((kk * 32 + fq * 8) ^ ((dr & 7) << 3)));
                oacc = __builtin_amdgcn_mfma_f32_16x16x32_bf16(ap, bv, oacc, 0, 0, 0);
            }
#pragma unroll
            for (int r = 0; r < 4; ++r) {
                int qrow = qt * 16 + fq * 4 + r;
                if (qrow < SEQ)
                    out[(size_t)(b * SEQ + qrow) * DMODEL + h * DHEAD + n * 16 + fr] = (bf16_t)oacc[r];
            }
        }
    }
}

// ---------------- layernorm: one wave per row of 512 ----------------
template <bool FINAL>
__global__ __launch_bounds__(256) void ln_k(const float* __restrict__ in,
                                            const float* __restrict__ gam,
                                            const float* __restrict__ bet,
                                            bf16_t* __restrict__ outb,
                                            float* __restrict__ outf)
{
    int row  = blockIdx.x * 4 + (threadIdx.x >> 6);
    int lane = threadIdx.x & 63;
    const float* x = in + (size_t)row * DMODEL + lane * 8;
    float4 v0 = *(const float4*)x;
    float4 v1 = *(const float4*)(x + 4);
    float s  = v0.x + v0.y + v0.z + v0.w + v1.x + v1.y + v1.z + v1.w;
    float s2 = v0.x * v0.x + v0.y * v0.y + v0.z * v0.z + v0.w * v0.w
             + v1.x * v1.x + v1.y * v1.y + v1.z * v1.z + v1.w * v1.w;
#pragma unroll
    for (int m = 1; m < 64; m <<= 1) { s += __shfl_xor(s, m); s2 += __shfl_xor(s2, m); }
    float mean = s * (1.f / DMODEL);
    float rstd = rsqrtf(s2 * (1.f / DMODEL) - mean * mean + 1e-5f);
    float4 g0 = *(const float4*)(gam + lane * 8), g1 = *(const float4*)(gam + lane * 8 + 4);
    float4 b0 = *(const float4*)(bet + lane * 8), b1 = *(const float4*)(bet + lane * 8 + 4);
    float y[8];
    y[0] = (v0.x - mean) * rstd * g0.x + b0.x;
    y[1] = (v0.y - mean) * rstd * g0.y + b0.y;
    y[2] = (v0.z - mean) * rstd * g0.z + b0.z;
    y[3] = (v0.w - mean) * rstd * g0.w + b0.w;
    y[4] = (v1.x - mean) * rstd * g1.x + b1.x;
    y[5] = (v1.y - mean) * rstd * g1.y + b1.y;
    y[6] = (v1.z - mean) * rstd * g1.z + b1.z;
    y[7] = (v1.w - mean) * rstd * g1.w + b1.w;
    bf16x8 ob;
#pragma unroll
    for (int j = 0; j < 8; ++j) ob[j] = (bf16_t)y[j];
    *(bf16x8*)(outb + (size_t)row * DMODEL + lane * 8) = ob;
    if (FINAL) {
        float4 o0 = {y[0], y[1], y[2], y[3]};
        float4 o1 = {y[4], y[5], y[6], y[7]};
        *(float4*)(outf + (size_t)row * DMODEL + lane * 8)     = o0;
        *(float4*)(outf + (size_t)row * DMODEL + lane * 8 + 4) = o1;
    }
}

// ---------------- driver ----------------
extern "C" void kernel_launch(void* const* d_in, const int* in_sizes, int n_in,
                              void* d_out, int out_size, void* d_ws, size_t ws_size,
                              hipStream_t stream)
{
    const int*   tok = (const int*)d_in[0];
    const float* emb = (const float*)d_in[1];
    const float* pos = (const float*)d_in[2];
    const float* Wk  = (const float*)d_in[3];
    const float* Wo  = (const float*)d_in[4];
    const float* W1  = (const float*)d_in[5];
    const float* b1  = (const float*)d_in[6];
    const float* W2  = (const float*)d_in[7];
    const float* b2  = (const float*)d_in[8];
    const float* gam = (const float*)d_in[9];
    const float* bet = (const float*)d_in[10];
    float* outp = (float*)d_out;

    char* ws = (char*)d_ws;
    size_t off = 0;
    auto alloc = [&](size_t bytes) {
        off = (off + 255) & ~(size_t)255;
        void* p = ws + off;
        off += bytes;
        return p;
    };
    bf16_t* WKT  = (bf16_t*)alloc((size_t)L_LAYERS * DMODEL * DMODEL * 2);
    bf16_t* WOT  = (bf16_t*)alloc((size_t)L_LAYERS * DMODEL * DMODEL * 2);
    bf16_t* W1T  = (bf16_t*)alloc((size_t)L_LAYERS * DMODEL * DFFN * 2);
    bf16_t* W2T  = (bf16_t*)alloc((size_t)L_LAYERS * DMODEL * DFFN * 2);
    bf16_t* buf0 = (bf16_t*)alloc((size_t)BN_ROWS * DMODEL * 2);   // x (bf16)
    bf16_t* buf1 = (bf16_t*)alloc((size_t)BN_ROWS * DMODEL * 2);   // z (bf16)
    bf16_t* kb   = (bf16_t*)alloc((size_t)BN_ROWS * DMODEL * 2);   // k = q = v
    bf16_t* ob   = (bf16_t*)alloc((size_t)BN_ROWS * DMODEL * 2);   // attn out
    bf16_t* h1b  = (bf16_t*)alloc((size_t)BN_ROWS * DFFN * 2);     // ffn hidden
    float*  tf   = (float*)alloc((size_t)BN_ROWS * DMODEL * 4);    // pre-LN f32

    // weights -> bf16 transposed [N][K]
    transpose_wk8<<<768, 256, 0, stream>>>(Wk, WKT);
    transpose_w8<<<768, 256, 0, stream>>>(Wo, WOT, DMODEL, DMODEL);
    transpose_w8<<<3072, 256, 0, stream>>>(W1, W1T, DMODEL, DFFN);
    transpose_w8<<<3072, 256, 0, stream>>>(W2, W2T, DFFN, DMODEL);

    embed_k<<<BN_ROWS, 128, 0, stream>>>(tok, emb, pos, buf0);

    for (int l = 0; l < L_LAYERS; ++l) {
        // k = x @ Wk   [BN,512] bf16
        gemm_bt<0, bf16_t><<<150 * 4, 256, 0, stream>>>(
            buf0, WKT + (size_t)l * DMODEL * DMODEL, kb, nullptr, nullptr,
            BN_ROWS, DMODEL, DMODEL, 4);
        // attention (Q=K=V=k)
        attn_k<<<BATCH * HEADS, 256, 0, stream>>>(kb, ob);
        // t = o @ Wo + x   (f32)
        gemm_bt<1, float><<<150 * 4, 256, 0, stream>>>(
            ob, WOT + (size_t)l * DMODEL * DMODEL, tf, nullptr, buf0,
            BN_ROWS, DMODEL, DMODEL, 4);
        // z = LN(t)
        ln_k<false><<<BN_ROWS / 4, 256, 0, stream>>>(
            tf, gam + l * DMODEL, bet + l * DMODEL, buf1, nullptr);
        // h1 = relu(z @ W1 + b1)  bf16
        gemm_bt<2, bf16_t><<<150 * 16, 256, 0, stream>>>(
            buf1, W1T + (size_t)l * DMODEL * DFFN, h1b, b1 + l * DFFN, nullptr,
            BN_ROWS, DMODEL, DFFN, 16);
        // t = h1 @ W2 + b2 + z   (f32)
        gemm_bt<3, float><<<150 * 4, 256, 0, stream>>>(
            h1b, W2T + (size_t)l * DMODEL * DFFN, tf, b2 + l * DMODEL, buf1,
            BN_ROWS, DFFN, DMODEL, 4);
        // x = LN(t)  (final layer also writes f32 output)
        if (l < L_LAYERS - 1)
            ln_k<false><<<BN_ROWS / 4, 256, 0, stream>>>(
                tf, gam + l * DMODEL, bet + l * DMODEL, buf0, nullptr);
        else
            ln_k<true><<<BN_ROWS / 4, 256, 0, stream>>>(
                tf, gam + l * DMODEL, bet + l * DMODEL, buf0, outp);
    }
}

// Round 2
// 1692.140 us; speedup vs baseline: 1.0556x; 1.0556x over previous
//
#include <hip/hip_runtime.h>

// ---- problem constants ----
#define L_LAYERS 6
#define HEADS    8
#define DMODEL   512
#define DHEAD    64
#define SEQ      300
#define BATCH    64
#define DFFN     2048
#define BN_ROWS  (BATCH*SEQ)   // 19200 = 75 * 256 exactly
#define NPAD     320           // SEQ padded to 20*16

typedef __bf16 bf16_t;
typedef bf16_t bf16x8 __attribute__((ext_vector_type(8)));
typedef bf16_t bf16x4 __attribute__((ext_vector_type(4)));
typedef float  f32x4  __attribute__((ext_vector_type(4)));

// async global->LDS, 16B per lane. LDS dest must be linear in lane order.
#define GLOAD16(gp, lp) __builtin_amdgcn_global_load_lds( \
    (__attribute__((address_space(1))) void*)(gp),        \
    (__attribute__((address_space(3))) void*)(lp), 16, 0, 0)

#define MEMBAR() asm volatile("" ::: "memory")
#define PHASE_BAR() do { MEMBAR(); __builtin_amdgcn_s_barrier(); MEMBAR(); } while (0)
#define VMCNT4() asm volatile("s_waitcnt vmcnt(4)" ::: "memory")

// ---------------- weight transpose + bf16 convert ----------------
__global__ __launch_bounds__(256) void transpose_w8(const float* __restrict__ w,
                                                    bf16_t* __restrict__ o,
                                                    int K, int Nc)
{
    int idx = blockIdx.x * 256 + threadIdx.x;   // over L*K/8*Nc
    int n   = idx % Nc;
    int r   = idx / Nc;
    int k8  = (r % (K / 8)) * 8;
    int l   = r / (K / 8);
    const float* wp = w + (size_t)l * K * Nc + (size_t)k8 * Nc + n;
    bf16x8 t;
#pragma unroll
    for (int j = 0; j < 8; ++j) t[j] = (bf16_t)wp[(size_t)j * Nc];
    *(bf16x8*)(o + (size_t)l * K * Nc + (size_t)n * K + k8) = t;
}

// Wk [L][H][D][DH] f32 -> o [L][h*64+e][d] bf16
__global__ __launch_bounds__(256) void transpose_wk8(const float* __restrict__ wk,
                                                     bf16_t* __restrict__ o)
{
    int idx = blockIdx.x * 256 + threadIdx.x;
    int e  = idx % DHEAD;
    int r  = idx / DHEAD;
    int d8 = (r % (DMODEL / 8)) * 8;
    r      = r / (DMODEL / 8);
    int h  = r % HEADS;
    int l  = r / HEADS;
    const float* wp = wk + (((size_t)(l * HEADS + h) * DMODEL + d8) * DHEAD + e);
    bf16x8 t;
#pragma unroll
    for (int j = 0; j < 8; ++j) t[j] = (bf16_t)wp[(size_t)j * DHEAD];
    *(bf16x8*)(o + (size_t)l * DMODEL * DMODEL + (size_t)(h * DHEAD + e) * DMODEL + d8) = t;
}

// ---------------- embedding ----------------
__global__ __launch_bounds__(128) void embed_k(const int* __restrict__ tok,
                                               const float* __restrict__ emb,
                                               const float* __restrict__ pos,
                                               bf16_t* __restrict__ xb)
{
    int row = blockIdx.x;
    int n   = row % SEQ;
    int tkn = tok[row];
    int c   = threadIdx.x * 4;
    float4 e = *(const float4*)(emb + (size_t)tkn * DMODEL + c);
    float4 p = *(const float4*)(pos + (size_t)n * DMODEL + c);
    bf16x4 o;
    o[0] = (bf16_t)(e.x + p.x); o[1] = (bf16_t)(e.y + p.y);
    o[2] = (bf16_t)(e.z + p.z); o[3] = (bf16_t)(e.w + p.w);
    *(bf16x4*)(xb + (size_t)row * DMODEL + c) = o;
}

// ---------------- 256x256 deep-pipelined GEMM ----------------
// C[19200,Nc] = A[19200,K] @ BT[Nc,K]^T, 8 waves (2Mx4N), per-wave 128x64.
// LDS: A dbuf [2][256][64], B dbuf [2][2 nq][128][64] (row-permuted halves).
// Schedule per K-tile t (4 phases, nq=ph>>1, kk=ph&1):
//   ph0: stage A-half0(t+1)->nbuf      ph1: stage A-half1(t+1)->nbuf, vmcnt(4)
//   ph2: stage B-nq0(t+2) ->buf        ph3: stage B-nq1(t+1)->nbuf,  vmcnt(4)
// Counted vmcnt keeps 4 loads in flight across every checkpoint.
template <int EPI, typename OUT_T>
__global__ __launch_bounds__(512, 2) void gemm256(const bf16_t* __restrict__ A,
                                                  const bf16_t* __restrict__ BT,
                                                  OUT_T* __restrict__ C,
                                                  const float* __restrict__ bias,
                                                  const bf16_t* __restrict__ resid,
                                                  int K, int Nc, int tiles_n)
{
    __shared__ bf16_t smem[65536];   // 128 KB
    bf16_t* As  = smem;              // [2][256][64]
    bf16_t* Bsm = smem + 32768;      // [2][2][128][64]

    const int t = threadIdx.x;
    // bijective XCD swizzle (m204)
    const int nwg = gridDim.x;
    const int q = nwg >> 3, r = nwg & 7;
    const int xc = blockIdx.x & 7, sq = blockIdx.x >> 3;
    const int lt = (xc < r ? xc * (q + 1) : r * (q + 1) + (xc - r) * q) + sq;
    const int tm = lt / tiles_n, tn = lt % tiles_n;

    const bf16_t* Ab = A  + (size_t)tm * 256 * K;
    const bf16_t* Bb = BT + (size_t)tn * 256 * K;
    const int lane = t & 63, wid = t >> 6;
    const int wr = wid >> 2, wc = wid & 3;
    const int fr = lane & 15, fq = lane >> 4;
    const int NT = K >> 6;

    auto stage_a = [&](int dbuf, int half, int kt) {
#pragma unroll
        for (int j = 0; j < 2; ++j) {
            int idx8 = (j * 512 + t) * 8;
            int rl   = idx8 >> 6;                       // 0..127
            int cg   = (idx8 & 63) ^ ((rl & 7) << 3);
            GLOAD16(Ab + (size_t)(half * 128 + rl) * K + kt * 64 + cg,
                    As + dbuf * 16384 + half * 8192 + idx8);
        }
    };
    auto stage_b = [&](int dbuf, int nq, int kt) {
#pragma unroll
        for (int j = 0; j < 2; ++j) {
            int idx8 = (j * 512 + t) * 8;
            int rl   = idx8 >> 6;
            int cg   = (idx8 & 63) ^ ((rl & 7) << 3);
            int grow = (rl >> 5) * 64 + nq * 32 + (rl & 31);
            GLOAD16(Bb + (size_t)grow * K + kt * 64 + cg,
                    Bsm + dbuf * 16384 + nq * 8192 + idx8);
        }
    };

    const f32x4 FZ = {0.f, 0.f, 0.f, 0.f};
    f32x4 acc[8][4];
#pragma unroll
    for (int m = 0; m < 8; ++m)
#pragma unroll
        for (int n = 0; n < 4; ++n) acc[m][n] = FZ;

    // prologue: tile0 full + B-nq0 of tile1
    stage_a(0, 0, 0); stage_a(0, 1, 0);
    stage_b(0, 0, 0); stage_b(0, 1, 0);
    stage_b(1, 0, 1);
    VMCNT4();
    PHASE_BAR();

    for (int tt = 0; tt < NT; ++tt) {
        const int buf = tt & 1, nbuf = buf ^ 1;
        const bf16_t* Ap = As + buf * 16384 + (wr * 128 + fr) * 64;
#pragma unroll
        for (int ph = 0; ph < 4; ++ph) {
            const int nq = ph >> 1, kk = ph & 1;
            const int ca = (kk * 32 + fq * 8) ^ ((fr & 7) << 3);
            bf16x8 af[8];
#pragma unroll
            for (int m = 0; m < 8; ++m)
                af[m] = *(const bf16x8*)(Ap + m * 1024 + ca);
            const bf16_t* Bp = Bsm + buf * 16384 + nq * 8192 + (wc * 32 + fr) * 64;
            bf16x8 b0 = *(const bf16x8*)(Bp + ca);
            bf16x8 b1 = *(const bf16x8*)(Bp + 1024 + ca);

            if (ph == 0) { if (tt + 1 < NT) stage_a(nbuf, 0, tt + 1); }
            if (ph == 1) { if (tt + 1 < NT) stage_a(nbuf, 1, tt + 1); VMCNT4(); }
            if (ph == 2) { if (tt + 2 < NT) stage_b(buf, 0, tt + 2); }
            if (ph == 3) { if (tt + 1 < NT) stage_b(nbuf, 1, tt + 1); VMCNT4(); }

            PHASE_BAR();
            __builtin_amdgcn_s_setprio(1);
#pragma unroll
            for (int m = 0; m < 8; ++m) {
                acc[m][nq * 2]     = __builtin_amdgcn_mfma_f32_16x16x32_bf16(af[m], b0, acc[m][nq * 2], 0, 0, 0);
                acc[m][nq * 2 + 1] = __builtin_amdgcn_mfma_f32_16x16x32_bf16(af[m], b1, acc[m][nq * 2 + 1], 0, 0, 0);
            }
            __builtin_amdgcn_s_setprio(0);
            PHASE_BAR();
        }
    }

    // epilogue
#pragma unroll
    for (int m = 0; m < 8; ++m) {
        const int rowg = tm * 256 + wr * 128 + m * 16 + fq * 4;
#pragma unroll
        for (int n = 0; n < 4; ++n) {
            const int colg = tn * 256 + wc * 64 + n * 16 + fr;
            float bv = (EPI == 2 || EPI == 3) ? bias[colg] : 0.f;
#pragma unroll
            for (int rr = 0; rr < 4; ++rr) {
                float v = acc[m][n][rr] + bv;
                if (EPI == 2) v = fmaxf(v, 0.f);
                if (EPI == 1 || EPI == 3) v += (float)resid[(size_t)(rowg + rr) * Nc + colg];
                C[(size_t)(rowg + rr) * Nc + colg] = (OUT_T)v;
            }
        }
    }
}

// ---------------- fused attention for one (b,h); exploits Q=K=V ----------------
__global__ __launch_bounds__(256) void attn_k(const bf16_t* __restrict__ kin,
                                              bf16_t* __restrict__ out)
{
    __shared__ bf16_t Kl[NPAD * 64];
    __shared__ bf16_t KT[64 * NPAD];
    __shared__ bf16_t Pl[4 * 16 * NPAD];

    const int bh = blockIdx.x;
    const int b  = bh >> 3, h = bh & 7;
    const bf16_t* kbase = kin + (size_t)b * SEQ * DMODEL + h * DHEAD;
    const int t  = threadIdx.x;
    const int rr = t >> 3;
    const int cg = (t & 7) * 8;

    for (int pass = 0; pass < NPAD / 32; ++pass) {
        int row = pass * 32 + rr;
        bf16x8 v;
        if (row < SEQ) v = *(const bf16x8*)(kbase + (size_t)row * DMODEL + cg);
        else {
#pragma unroll
            for (int j = 0; j < 8; ++j) v[j] = (bf16_t)0.f;
        }
        *(bf16x8*)(Kl + row * 64 + (cg ^ ((row & 7) << 3))) = v;
#pragma unroll
        for (int j = 0; j < 8; ++j) {
            int col = cg + j;
            KT[col * NPAD + (row ^ ((col & 7) << 3))] = v[j];
        }
    }
    __syncthreads();

    const int lane = t & 63, w = t >> 6;
    const int fr = lane & 15, fq = lane >> 4;
    const float scale = 0.044194173824159216f;   // 1/sqrt(512)
    const f32x4 FZ = {0.f, 0.f, 0.f, 0.f};

    for (int i = 0; i < 5; ++i) {
        int qt = w * 5 + i;
        f32x4 s[20];
#pragma unroll
        for (int ct = 0; ct < 20; ++ct) s[ct] = FZ;
#pragma unroll
        for (int kk = 0; kk < 2; ++kk) {
            int qrow = qt * 16 + fr;
            bf16x8 aq = *(const bf16x8*)(Kl + qrow * 64 + ((kk * 32 + fq * 8) ^ ((qrow & 7) << 3)));
#pragma unroll
            for (int ct = 0; ct < 20; ++ct) {
                int krow = ct * 16 + fr;
                bf16x8 bk = *(const bf16x8*)(Kl + krow * 64 + ((kk * 32 + fq * 8) ^ ((krow & 7) << 3)));
                s[ct] = __builtin_amdgcn_mfma_f32_16x16x32_bf16(aq, bk, s[ct], 0, 0, 0);
            }
        }
#pragma unroll
        for (int r = 0; r < 4; ++r) {
            float mx = -1e30f;
#pragma unroll
            for (int ct = 0; ct < 20; ++ct) {
                float v = s[ct][r] * scale;
                if (ct * 16 + fr < SEQ) mx = fmaxf(mx, v);
            }
            mx = fmaxf(mx, __shfl_xor(mx, 1));
            mx = fmaxf(mx, __shfl_xor(mx, 2));
            mx = fmaxf(mx, __shfl_xor(mx, 4));
            mx = fmaxf(mx, __shfl_xor(mx, 8));
            float p[20];
            float sm = 0.f;
#pragma unroll
            for (int ct = 0; ct < 20; ++ct) {
                float v = (ct * 16 + fr < SEQ) ? __expf(s[ct][r] * scale - mx) : 0.f;
                p[ct] = v; sm += v;
            }
            sm += __shfl_xor(sm, 1); sm += __shfl_xor(sm, 2);
            sm += __shfl_xor(sm, 4); sm += __shfl_xor(sm, 8);
            float rinv = 1.f / sm;
            int pr = fq * 4 + r;
#pragma unroll
            for (int ct = 0; ct < 20; ++ct) {
                int col = ct * 16 + fr;
                Pl[(w * 16 + pr) * NPAD + (col ^ ((pr & 7) << 3))] = (bf16_t)(p[ct] * rinv);
            }
        }
#pragma unroll
        for (int n = 0; n < 4; ++n) {
            f32x4 oacc = FZ;
#pragma unroll
            for (int kk = 0; kk < 10; ++kk) {
                bf16x8 ap = *(const bf16x8*)(Pl + (w * 16 + fr) * NPAD + ((kk * 32 + fq * 8) ^ ((fr & 7) << 3)));
                int dr = n * 16 + fr;
                bf16x8 bv = *(const bf16x8*)(KT + dr * NPAD + ((kk * 32 + fq * 8) ^ ((dr & 7) << 3)));
                oacc = __builtin_amdgcn_mfma_f32_16x16x32_bf16(ap, bv, oacc, 0, 0, 0);
            }
#pragma unroll
            for (int r = 0; r < 4; ++r) {
                int qrow = qt * 16 + fq * 4 + r;
                if (qrow < SEQ)
                    out[(size_t)(b * SEQ + qrow) * DMODEL + h * DHEAD + n * 16 + fr] = (bf16_t)oacc[r];
            }
        }
    }
}

// ---------------- layernorm: one wave per row of 512 ----------------
template <bool FINAL>
__global__ __launch_bounds__(256) void ln_k(const float* __restrict__ in,
                                            const float* __restrict__ gam,
                                            const float* __restrict__ bet,
                                            bf16_t* __restrict__ outb,
                                            float* __restrict__ outf)
{
    int row  = blockIdx.x * 4 + (threadIdx.x >> 6);
    int lane = threadIdx.x & 63;
    const float* x = in + (size_t)row * DMODEL + lane * 8;
    float4 v0 = *(const float4*)x;
    float4 v1 = *(const float4*)(x + 4);
    float s  = v0.x + v0.y + v0.z + v0.w + v1.x + v1.y + v1.z + v1.w;
    float s2 = v0.x * v0.x + v0.y * v0.y + v0.z * v0.z + v0.w * v0.w
             + v1.x * v1.x + v1.y * v1.y + v1.z * v1.z + v1.w * v1.w;
#pragma unroll
    for (int m = 1; m < 64; m <<= 1) { s += __shfl_xor(s, m); s2 += __shfl_xor(s2, m); }
    float mean = s * (1.f / DMODEL);
    float rstd = rsqrtf(s2 * (1.f / DMODEL) - mean * mean + 1e-5f);
    float4 g0 = *(const float4*)(gam + lane * 8), g1 = *(const float4*)(gam + lane * 8 + 4);
    float4 b0 = *(const float4*)(bet + lane * 8), b1 = *(const float4*)(bet + lane * 8 + 4);
    float y[8];
    y[0] = (v0.x - mean) * rstd * g0.x + b0.x;
    y[1] = (v0.y - mean) * rstd * g0.y + b0.y;
    y[2] = (v0.z - mean) * rstd * g0.z + b0.z;
    y[3] = (v0.w - mean) * rstd * g0.w + b0.w;
    y[4] = (v1.x - mean) * rstd * g1.x + b1.x;
    y[5] = (v1.y - mean) * rstd * g1.y + b1.y;
    y[6] = (v1.z - mean) * rstd * g1.z + b1.z;
    y[7] = (v1.w - mean) * rstd * g1.w + b1.w;
    bf16x8 ob;
#pragma unroll
    for (int j = 0; j < 8; ++j) ob[j] = (bf16_t)y[j];
    *(bf16x8*)(outb + (size_t)row * DMODEL + lane * 8) = ob;
    if (FINAL) {
        float4 o0 = {y[0], y[1], y[2], y[3]};
        float4 o1 = {y[4], y[5], y[6], y[7]};
        *(float4*)(outf + (size_t)row * DMODEL + lane * 8)     = o0;
        *(float4*)(outf + (size_t)row * DMODEL + lane * 8 + 4) = o1;
    }
}

// ---------------- driver ----------------
extern "C" void kernel_launch(void* const* d_in, const int* in_sizes, int n_in,
                              void* d_out, int out_size, void* d_ws, size_t ws_size,
                              hipStream_t stream)
{
    const int*   tok = (const int*)d_in[0];
    const float* emb = (const float*)d_in[1];
    const float* pos = (const float*)d_in[2];
    const float* Wk  = (const float*)d_in[3];
    const float* Wo  = (const float*)d_in[4];
    const float* W1  = (const float*)d_in[5];
    const float* b1  = (const float*)d_in[6];
    const float* W2  = (const float*)d_in[7];
    const float* b2  = (const float*)d_in[8];
    const float* gam = (const float*)d_in[9];
    const float* bet = (const float*)d_in[10];
    float* outp = (float*)d_out;

    char* ws = (char*)d_ws;
    size_t off = 0;
    auto alloc = [&](size_t bytes) {
        off = (off + 255) & ~(size_t)255;
        void* p = ws + off;
        off += bytes;
        return p;
    };
    bf16_t* WKT  = (bf16_t*)alloc((size_t)L_LAYERS * DMODEL * DMODEL * 2);
    bf16_t* WOT  = (bf16_t*)alloc((size_t)L_LAYERS * DMODEL * DMODEL * 2);
    bf16_t* W1T  = (bf16_t*)alloc((size_t)L_LAYERS * DMODEL * DFFN * 2);
    bf16_t* W2T  = (bf16_t*)alloc((size_t)L_LAYERS * DMODEL * DFFN * 2);
    bf16_t* buf0 = (bf16_t*)alloc((size_t)BN_ROWS * DMODEL * 2);
    bf16_t* buf1 = (bf16_t*)alloc((size_t)BN_ROWS * DMODEL * 2);
    bf16_t* kb   = (bf16_t*)alloc((size_t)BN_ROWS * DMODEL * 2);
    bf16_t* ob   = (bf16_t*)alloc((size_t)BN_ROWS * DMODEL * 2);
    bf16_t* h1b  = (bf16_t*)alloc((size_t)BN_ROWS * DFFN * 2);
    float*  tf   = (float*)alloc((size_t)BN_ROWS * DMODEL * 4);

    transpose_wk8<<<768, 256, 0, stream>>>(Wk, WKT);
    transpose_w8<<<768, 256, 0, stream>>>(Wo, WOT, DMODEL, DMODEL);
    transpose_w8<<<3072, 256, 0, stream>>>(W1, W1T, DMODEL, DFFN);
    transpose_w8<<<3072, 256, 0, stream>>>(W2, W2T, DFFN, DMODEL);

    embed_k<<<BN_ROWS, 128, 0, stream>>>(tok, emb, pos, buf0);

    for (int l = 0; l < L_LAYERS; ++l) {
        // k = x @ Wk   [BN,512] bf16
        gemm256<0, bf16_t><<<75 * 2, 512, 0, stream>>>(
            buf0, WKT + (size_t)l * DMODEL * DMODEL, kb, nullptr, nullptr,
            DMODEL, DMODEL, 2);
        // attention (Q=K=V=k)
        attn_k<<<BATCH * HEADS, 256, 0, stream>>>(kb, ob);
        // t = o @ Wo + x   (f32)
        gemm256<1, float><<<75 * 2, 512, 0, stream>>>(
            ob, WOT + (size_t)l * DMODEL * DMODEL, tf, nullptr, buf0,
            DMODEL, DMODEL, 2);
        // z = LN(t)
        ln_k<false><<<BN_ROWS / 4, 256, 0, stream>>>(
            tf, gam + l * DMODEL, bet + l * DMODEL, buf1, nullptr);
        // h1 = relu(z @ W1 + b1)  bf16
        gemm256<2, bf16_t><<<75 * 8, 512, 0, stream>>>(
            buf1, W1T + (size_t)l * DMODEL * DFFN, h1b, b1 + l * DFFN, nullptr,
            DMODEL, DFFN, 8);
        // t = h1 @ W2 + b2 + z   (f32)
        gemm256<3, float><<<75 * 2, 512, 0, stream>>>(
            h1b, W2T + (size_t)l * DMODEL * DFFN, tf, b2 + l * DMODEL, buf1,
            DFFN, DMODEL, 2);
        // x = LN(t)
        if (l < L_LAYERS - 1)
            ln_k<false><<<BN_ROWS / 4, 256, 0, stream>>>(
                tf, gam + l * DMODEL, bet + l * DMODEL, buf0, nullptr);
        else
            ln_k<true><<<BN_ROWS / 4, 256, 0, stream>>>(
                tf, gam + l * DMODEL, bet + l * DMODEL, buf0, outp);
    }
}

// Round 5
// 1566.551 us; speedup vs baseline: 1.1402x; 1.0802x over previous
//
#include <hip/hip_runtime.h>

// ---- problem constants ----
#define L_LAYERS 6
#define HEADS    8
#define DMODEL   512
#define DHEAD    64
#define SEQ      300
#define BATCH    64
#define DFFN     2048
#define BN_ROWS  (BATCH*SEQ)   // 19200 = 75 * 256 = 150 * 128 exactly
#define NPAD     320           // SEQ padded to 20*16

typedef __bf16 bf16_t;
typedef bf16_t bf16x8 __attribute__((ext_vector_type(8)));
typedef bf16_t bf16x4 __attribute__((ext_vector_type(4)));
typedef float  f32x4  __attribute__((ext_vector_type(4)));

// async global->LDS, 16B per lane. LDS dest must be linear in lane order.
#define GLOAD16(gp, lp) __builtin_amdgcn_global_load_lds( \
    (__attribute__((address_space(1))) void*)(gp),        \
    (__attribute__((address_space(3))) void*)(lp), 16, 0, 0)

#define MEMBAR() asm volatile("" ::: "memory")
#define PHASE_BAR() do { MEMBAR(); __builtin_amdgcn_s_barrier(); MEMBAR(); } while (0)
#define VMCNT4() asm volatile("s_waitcnt vmcnt(4)" ::: "memory")
#define VMCNT0() asm volatile("s_waitcnt vmcnt(0)" ::: "memory")

// ---------------- weight transpose + bf16 convert ----------------
__global__ __launch_bounds__(256) void transpose_w8(const float* __restrict__ w,
                                                    bf16_t* __restrict__ o,
                                                    int K, int Nc)
{
    int idx = blockIdx.x * 256 + threadIdx.x;   // over L*K/8*Nc
    int n   = idx % Nc;
    int r   = idx / Nc;
    int k8  = (r % (K / 8)) * 8;
    int l   = r / (K / 8);
    const float* wp = w + (size_t)l * K * Nc + (size_t)k8 * Nc + n;
    bf16x8 t;
#pragma unroll
    for (int j = 0; j < 8; ++j) t[j] = (bf16_t)wp[(size_t)j * Nc];
    *(bf16x8*)(o + (size_t)l * K * Nc + (size_t)n * K + k8) = t;
}

// Wk [L][H][D][DH] f32 -> o [L][h*64+e][d] bf16
__global__ __launch_bounds__(256) void transpose_wk8(const float* __restrict__ wk,
                                                     bf16_t* __restrict__ o)
{
    int idx = blockIdx.x * 256 + threadIdx.x;
    int e  = idx % DHEAD;
    int r  = idx / DHEAD;
    int d8 = (r % (DMODEL / 8)) * 8;
    r      = r / (DMODEL / 8);
    int h  = r % HEADS;
    int l  = r / HEADS;
    const float* wp = wk + (((size_t)(l * HEADS + h) * DMODEL + d8) * DHEAD + e);
    bf16x8 t;
#pragma unroll
    for (int j = 0; j < 8; ++j) t[j] = (bf16_t)wp[(size_t)j * DHEAD];
    *(bf16x8*)(o + (size_t)l * DMODEL * DMODEL + (size_t)(h * DHEAD + e) * DMODEL + d8) = t;
}

// ---------------- embedding ----------------
__global__ __launch_bounds__(128) void embed_k(const int* __restrict__ tok,
                                               const float* __restrict__ emb,
                                               const float* __restrict__ pos,
                                               bf16_t* __restrict__ xb)
{
    int row = blockIdx.x;
    int n   = row % SEQ;
    int tkn = tok[row];
    int c   = threadIdx.x * 4;
    float4 e = *(const float4*)(emb + (size_t)tkn * DMODEL + c);
    float4 p = *(const float4*)(pos + (size_t)n * DMODEL + c);
    bf16x4 o;
    o[0] = (bf16_t)(e.x + p.x); o[1] = (bf16_t)(e.y + p.y);
    o[2] = (bf16_t)(e.z + p.z); o[3] = (bf16_t)(e.w + p.w);
    *(bf16x4*)(xb + (size_t)row * DMODEL + c) = o;
}

// ---------------- 256x256 deep-pipelined GEMM (8 waves, 24 ds_reads/K-tile) ----------------
// Phases kk-outer: ph0(kk0,nq0) ph1(kk0,nq1) ph2(kk1,nq0) ph3(kk1,nq1).
// af[8] read once per kk, reused across both nq phases. 3 barriers/tile.
// Stages: ph0:A0(t+1)+vmcnt4, ph1:A1(t+1), ph2:B1(t+1), ph3:B0(t+2)+vmcnt4.
// Tile-entry invariant: [B1(t), B0(t+1)] in flight; everything else landed.
template <int EPI, typename OUT_T>
__global__ __launch_bounds__(512, 2) void gemm256(const bf16_t* __restrict__ A,
                                                  const bf16_t* __restrict__ BT,
                                                  OUT_T* __restrict__ C,
                                                  const float* __restrict__ bias,
                                                  const bf16_t* __restrict__ resid,
                                                  int K, int Nc, int tiles_n)
{
    __shared__ bf16_t smem[65536];   // 128 KB
    bf16_t* As  = smem;              // [2][256][64]
    bf16_t* Bsm = smem + 32768;      // [2][2 nq][128][64]

    const int t = threadIdx.x;
    const int nwg = gridDim.x;
    const int q = nwg >> 3, r = nwg & 7;
    const int xc = blockIdx.x & 7, sq = blockIdx.x >> 3;
    const int lt = (xc < r ? xc * (q + 1) : r * (q + 1) + (xc - r) * q) + sq;
    const int tm = lt / tiles_n, tn = lt % tiles_n;

    const bf16_t* Ab = A  + (size_t)tm * 256 * K;
    const bf16_t* Bb = BT + (size_t)tn * 256 * K;
    const int lane = t & 63, wid = t >> 6;
    const int wr = wid >> 2, wc = wid & 3;
    const int fr = lane & 15, fq = lane >> 4;
    const int NT = K >> 6;

    auto stage_a = [&](int dbuf, int half, int kt) {
#pragma unroll
        for (int j = 0; j < 2; ++j) {
            int idx8 = (j * 512 + t) * 8;
            int rl   = idx8 >> 6;
            int cg   = (idx8 & 63) ^ ((rl & 7) << 3);
            GLOAD16(Ab + (size_t)(half * 128 + rl) * K + kt * 64 + cg,
                    As + dbuf * 16384 + half * 8192 + idx8);
        }
    };
    auto stage_b = [&](int dbuf, int nq, int kt) {
#pragma unroll
        for (int j = 0; j < 2; ++j) {
            int idx8 = (j * 512 + t) * 8;
            int rl   = idx8 >> 6;
            int cg   = (idx8 & 63) ^ ((rl & 7) << 3);
            int grow = (rl >> 5) * 64 + nq * 32 + (rl & 31);
            GLOAD16(Bb + (size_t)grow * K + kt * 64 + cg,
                    Bsm + dbuf * 16384 + nq * 8192 + idx8);
        }
    };

    const f32x4 FZ = {0.f, 0.f, 0.f, 0.f};
    f32x4 acc[8][4];
#pragma unroll
    for (int m = 0; m < 8; ++m)
#pragma unroll
        for (int n = 0; n < 4; ++n) acc[m][n] = FZ;

    // prologue: lands A(0),B0(0); leaves [B1(0), B0(1)] in flight
    stage_a(0, 0, 0); stage_a(0, 1, 0); stage_b(0, 0, 0);
    stage_b(0, 1, 0); stage_b(1, 0, 1);
    VMCNT4();
    PHASE_BAR();

    for (int tt = 0; tt < NT; ++tt) {
        const int buf = tt & 1, nbuf = buf ^ 1;
        const bf16_t* Ap  = As  + buf * 16384 + (wr * 128 + fr) * 64;
        const bf16_t* Bp0 = Bsm + buf * 16384 + (wc * 32 + fr) * 64;
        const bf16_t* Bp1 = Bp0 + 8192;
        const int ca0 = (fq * 8) ^ ((fr & 7) << 3);
        const int ca1 = ca0 ^ 32;
        bf16x8 af[8], b0, b1;

        // ---- ph0: kk0, nq0 ----
#pragma unroll
        for (int m = 0; m < 8; ++m) af[m] = *(const bf16x8*)(Ap + m * 1024 + ca0);
        b0 = *(const bf16x8*)(Bp0 + ca0);
        b1 = *(const bf16x8*)(Bp0 + 1024 + ca0);
        if (tt + 1 < NT) { stage_a(nbuf, 0, tt + 1); VMCNT4(); }
        PHASE_BAR();
        __builtin_amdgcn_s_setprio(1);
#pragma unroll
        for (int m = 0; m < 8; ++m) {
            acc[m][0] = __builtin_amdgcn_mfma_f32_16x16x32_bf16(af[m], b0, acc[m][0], 0, 0, 0);
            acc[m][1] = __builtin_amdgcn_mfma_f32_16x16x32_bf16(af[m], b1, acc[m][1], 0, 0, 0);
        }
        __builtin_amdgcn_s_setprio(0);

        // ---- ph1: kk0, nq1 (af reused) ----
        b0 = *(const bf16x8*)(Bp1 + ca0);
        b1 = *(const bf16x8*)(Bp1 + 1024 + ca0);
        if (tt + 1 < NT) stage_a(nbuf, 1, tt + 1);
        __builtin_amdgcn_s_setprio(1);
#pragma unroll
        for (int m = 0; m < 8; ++m) {
            acc[m][2] = __builtin_amdgcn_mfma_f32_16x16x32_bf16(af[m], b0, acc[m][2], 0, 0, 0);
            acc[m][3] = __builtin_amdgcn_mfma_f32_16x16x32_bf16(af[m], b1, acc[m][3], 0, 0, 0);
        }
        __builtin_amdgcn_s_setprio(0);

        // ---- ph2: kk1, nq0 ----
#pragma unroll
        for (int m = 0; m < 8; ++m) af[m] = *(const bf16x8*)(Ap + m * 1024 + ca1);
        b0 = *(const bf16x8*)(Bp0 + ca1);
        b1 = *(const bf16x8*)(Bp0 + 1024 + ca1);
        if (tt + 1 < NT) stage_b(nbuf, 1, tt + 1);
        __builtin_amdgcn_s_setprio(1);
#pragma unroll
        for (int m = 0; m < 8; ++m) {
            acc[m][0] = __builtin_amdgcn_mfma_f32_16x16x32_bf16(af[m], b0, acc[m][0], 0, 0, 0);
            acc[m][1] = __builtin_amdgcn_mfma_f32_16x16x32_bf16(af[m], b1, acc[m][1], 0, 0, 0);
        }
        __builtin_amdgcn_s_setprio(0);
        PHASE_BAR();   // WAR: all nq0 reads done before ph3 overwrites buf-nq0

        // ---- ph3: kk1, nq1 ----
        b0 = *(const bf16x8*)(Bp1 + ca1);
        b1 = *(const bf16x8*)(Bp1 + 1024 + ca1);
        if (tt + 2 < NT) stage_b(buf, 0, tt + 2);
        __builtin_amdgcn_s_setprio(1);
#pragma unroll
        for (int m = 0; m < 8; ++m) {
            acc[m][2] = __builtin_amdgcn_mfma_f32_16x16x32_bf16(af[m], b0, acc[m][2], 0, 0, 0);
            acc[m][3] = __builtin_amdgcn_mfma_f32_16x16x32_bf16(af[m], b1, acc[m][3], 0, 0, 0);
        }
        __builtin_amdgcn_s_setprio(0);
        if (tt + 2 < NT) { VMCNT4(); } else { VMCNT0(); }
        PHASE_BAR();   // tile-end: A(t+1), B0(t+1) landed
    }

    // epilogue
#pragma unroll
    for (int m = 0; m < 8; ++m) {
        const int rowg = tm * 256 + wr * 128 + m * 16 + fq * 4;
#pragma unroll
        for (int n = 0; n < 4; ++n) {
            const int colg = tn * 256 + wc * 64 + n * 16 + fr;
            float bv = (EPI == 2 || EPI == 3) ? bias[colg] : 0.f;
#pragma unroll
            for (int rr = 0; rr < 4; ++rr) {
                float v = acc[m][n][rr] + bv;
                if (EPI == 2) v = fmaxf(v, 0.f);
                if (EPI == 1 || EPI == 3) v += (float)resid[(size_t)(rowg + rr) * Nc + colg];
                C[(size_t)(rowg + rr) * Nc + colg] = (OUT_T)v;
            }
        }
    }
}

// ---------------- 128x128 GEMM, 64 KB LDS -> 2 blocks/CU (cross-block hiding) ----------------
template <int EPI, typename OUT_T>
__global__ __launch_bounds__(256, 2) void gemm128(const bf16_t* __restrict__ A,
                                                  const bf16_t* __restrict__ BT,
                                                  OUT_T* __restrict__ C,
                                                  const float* __restrict__ bias,
                                                  const bf16_t* __restrict__ resid,
                                                  int K, int Nc, int tiles_n)
{
    __shared__ bf16_t smem[32768];   // 64 KB: A[2][128][64] + B[2][128][64]
    bf16_t* As = smem;
    bf16_t* Bs = smem + 16384;

    const int t = threadIdx.x;
    const int nwg = gridDim.x;
    const int q = nwg >> 3, r = nwg & 7;
    const int xc = blockIdx.x & 7, sq = blockIdx.x >> 3;
    const int lt = (xc < r ? xc * (q + 1) : r * (q + 1) + (xc - r) * q) + sq;
    const int tm = lt / tiles_n, tn = lt % tiles_n;

    const bf16_t* Ab = A  + (size_t)tm * 128 * K;
    const bf16_t* Bb = BT + (size_t)tn * 128 * K;
    const int lane = t & 63, wid = t >> 6;
    const int wr = wid >> 1, wc = wid & 1;
    const int fr = lane & 15, fq = lane >> 4;
    const int NT = K >> 6;

    auto stage = [&](bf16_t* dst, const bf16_t* src, int kt) {
#pragma unroll
        for (int j = 0; j < 4; ++j) {
            int idx8 = (j * 256 + t) * 8;
            int rl   = idx8 >> 6;
            int cg   = (idx8 & 63) ^ ((rl & 7) << 3);
            GLOAD16(src + (size_t)rl * K + kt * 64 + cg, dst + idx8);
        }
    };

    const f32x4 FZ = {0.f, 0.f, 0.f, 0.f};
    f32x4 acc[4][4];
#pragma unroll
    for (int m = 0; m < 4; ++m)
#pragma unroll
        for (int n = 0; n < 4; ++n) acc[m][n] = FZ;

    stage(As, Ab, 0); stage(Bs, Bb, 0);
    VMCNT0(); PHASE_BAR();

    for (int tt = 0; tt < NT; ++tt) {
        const int buf = tt & 1, nbuf = buf ^ 1;
        const bf16_t* Ap = As + buf * 8192 + (wr * 64 + fr) * 64;
        const bf16_t* Bp = Bs + buf * 8192 + (wc * 64 + fr) * 64;
        const int ca0 = (fq * 8) ^ ((fr & 7) << 3);
        const int ca1 = ca0 ^ 32;
        bf16x8 af[4], bfr[4];
#pragma unroll
        for (int m = 0; m < 4; ++m) af[m] = *(const bf16x8*)(Ap + m * 1024 + ca0);
#pragma unroll
        for (int n = 0; n < 4; ++n) bfr[n] = *(const bf16x8*)(Bp + n * 1024 + ca0);
        if (tt + 1 < NT) { stage(As + nbuf * 8192, Ab, tt + 1); stage(Bs + nbuf * 8192, Bb, tt + 1); }
        __builtin_amdgcn_s_setprio(1);
#pragma unroll
        for (int m = 0; m < 4; ++m)
#pragma unroll
            for (int n = 0; n < 4; ++n)
                acc[m][n] = __builtin_amdgcn_mfma_f32_16x16x32_bf16(af[m], bfr[n], acc[m][n], 0, 0, 0);
        __builtin_amdgcn_s_setprio(0);
#pragma unroll
        for (int m = 0; m < 4; ++m) af[m] = *(const bf16x8*)(Ap + m * 1024 + ca1);
#pragma unroll
        for (int n = 0; n < 4; ++n) bfr[n] = *(const bf16x8*)(Bp + n * 1024 + ca1);
        __builtin_amdgcn_s_setprio(1);
#pragma unroll
        for (int m = 0; m < 4; ++m)
#pragma unroll
            for (int n = 0; n < 4; ++n)
                acc[m][n] = __builtin_amdgcn_mfma_f32_16x16x32_bf16(af[m], bfr[n], acc[m][n], 0, 0, 0);
        __builtin_amdgcn_s_setprio(0);
        VMCNT0(); PHASE_BAR();
    }

#pragma unroll
    for (int m = 0; m < 4; ++m) {
#pragma unroll
        for (int n = 0; n < 4; ++n) {
            int colg = tn * 128 + wc * 64 + n * 16 + fr;
            float bv = (EPI == 2 || EPI == 3) ? bias[colg] : 0.f;
#pragma unroll
            for (int rr2 = 0; rr2 < 4; ++rr2) {
                int rowg = tm * 128 + wr * 64 + m * 16 + fq * 4 + rr2;
                float v = acc[m][n][rr2] + bv;
                if (EPI == 2) v = fmaxf(v, 0.f);
                if (EPI == 1 || EPI == 3) v += (float)resid[(size_t)rowg * Nc + colg];
                C[(size_t)rowg * Nc + colg] = (OUT_T)v;
            }
        }
    }
}

// ---------------- fused attention for one (b,h); exploits Q=K=V ----------------
__global__ __launch_bounds__(256) void attn_k(const bf16_t* __restrict__ kin,
                                              bf16_t* __restrict__ out)
{
    __shared__ bf16_t Kl[NPAD * 64];
    __shared__ bf16_t KT[64 * NPAD];
    __shared__ bf16_t Pl[4 * 16 * NPAD];

    const int bh = blockIdx.x;
    const int b  = bh >> 3, h = bh & 7;
    const bf16_t* kbase = kin + (size_t)b * SEQ * DMODEL + h * DHEAD;
    const int t  = threadIdx.x;
    const int rr = t >> 3;
    const int cg = (t & 7) * 8;

    for (int pass = 0; pass < NPAD / 32; ++pass) {
        int row = pass * 32 + rr;
        bf16x8 v;
        if (row < SEQ) v = *(const bf16x8*)(kbase + (size_t)row * DMODEL + cg);
        else {
#pragma unroll
            for (int j = 0; j < 8; ++j) v[j] = (bf16_t)0.f;
        }
        *(bf16x8*)(Kl + row * 64 + (cg ^ ((row & 7) << 3))) = v;
#pragma unroll
        for (int j = 0; j < 8; ++j) {
            int col = cg + j;
            KT[col * NPAD + (row ^ ((col & 7) << 3))] = v[j];
        }
    }
    __syncthreads();

    const int lane = t & 63, w = t >> 6;
    const int fr = lane & 15, fq = lane >> 4;
    const float scale = 0.044194173824159216f;   // 1/sqrt(512)
    const f32x4 FZ = {0.f, 0.f, 0.f, 0.f};

    for (int i = 0; i < 5; ++i) {
        int qt = w * 5 + i;
        f32x4 s[20];
#pragma unroll
        for (int ct = 0; ct < 20; ++ct) s[ct] = FZ;
#pragma unroll
        for (int kk = 0; kk < 2; ++kk) {
            int qrow = qt * 16 + fr;
            bf16x8 aq = *(const bf16x8*)(Kl + qrow * 64 + ((kk * 32 + fq * 8) ^ ((qrow & 7) << 3)));
#pragma unroll
            for (int ct = 0; ct < 20; ++ct) {
                int krow = ct * 16 + fr;
                bf16x8 bk = *(const bf16x8*)(Kl + krow * 64 + ((kk * 32 + fq * 8) ^ ((krow & 7) << 3)));
                s[ct] = __builtin_amdgcn_mfma_f32_16x16x32_bf16(aq, bk, s[ct], 0, 0, 0);
            }
        }
#pragma unroll
        for (int r = 0; r < 4; ++r) {
            float mx = -1e30f;
#pragma unroll
            for (int ct = 0; ct < 20; ++ct) {
                float v = s[ct][r] * scale;
                if (ct * 16 + fr < SEQ) mx = fmaxf(mx, v);
            }
            mx = fmaxf(mx, __shfl_xor(mx, 1));
            mx = fmaxf(mx, __shfl_xor(mx, 2));
            mx = fmaxf(mx, __shfl_xor(mx, 4));
            mx = fmaxf(mx, __shfl_xor(mx, 8));
            float p[20];
            float sm = 0.f;
#pragma unroll
            for (int ct = 0; ct < 20; ++ct) {
                float v = (ct * 16 + fr < SEQ) ? __expf(s[ct][r] * scale - mx) : 0.f;
                p[ct] = v; sm += v;
            }
            sm += __shfl_xor(sm, 1); sm += __shfl_xor(sm, 2);
            sm += __shfl_xor(sm, 4); sm += __shfl_xor(sm, 8);
            float rinv = 1.f / sm;
            int pr = fq * 4 + r;
#pragma unroll
            for (int ct = 0; ct < 20; ++ct) {
                int col = ct * 16 + fr;
                Pl[(w * 16 + pr) * NPAD + (col ^ ((pr & 7) << 3))] = (bf16_t)(p[ct] * rinv);
            }
        }
#pragma unroll
        for (int n = 0; n < 4; ++n) {
            f32x4 oacc = FZ;
#pragma unroll
            for (int kk = 0; kk < 10; ++kk) {
                bf16x8 ap = *(const bf16x8*)(Pl + (w * 16 + fr) * NPAD + ((kk * 32 + fq * 8) ^ ((fr & 7) << 3)));
                int dr = n * 16 + fr;
                bf16x8 bv = *(const bf16x8*)(KT + dr * NPAD + ((kk * 32 + fq * 8) ^ ((dr & 7) << 3)));
                oacc = __builtin_amdgcn_mfma_f32_16x16x32_bf16(ap, bv, oacc, 0, 0, 0);
            }
#pragma unroll
            for (int r = 0; r < 4; ++r) {
                int qrow = qt * 16 + fq * 4 + r;
                if (qrow < SEQ)
                    out[(size_t)(b * SEQ + qrow) * DMODEL + h * DHEAD + n * 16 + fr] = (bf16_t)oacc[r];
            }
        }
    }
}

// ---------------- layernorm: one wave per row of 512 ----------------
template <bool FINAL>
__global__ __launch_bounds__(256) void ln_k(const float* __restrict__ in,
                                            const float* __restrict__ gam,
                                            const float* __restrict__ bet,
                                            bf16_t* __restrict__ outb,
                                            float* __restrict__ outf)
{
    int row  = blockIdx.x * 4 + (threadIdx.x >> 6);
    int lane = threadIdx.x & 63;
    const float* x = in + (size_t)row * DMODEL + lane * 8;
    float4 v0 = *(const float4*)x;
    float4 v1 = *(const float4*)(x + 4);
    float s  = v0.x + v0.y + v0.z + v0.w + v1.x + v1.y + v1.z + v1.w;
    float s2 = v0.x * v0.x + v0.y * v0.y + v0.z * v0.z + v0.w * v0.w
             + v1.x * v1.x + v1.y * v1.y + v1.z * v1.z + v1.w * v1.w;
#pragma unroll
    for (int m = 1; m < 64; m <<= 1) { s += __shfl_xor(s, m); s2 += __shfl_xor(s2, m); }
    float mean = s * (1.f / DMODEL);
    float rstd = rsqrtf(s2 * (1.f / DMODEL) - mean * mean + 1e-5f);
    float4 g0 = *(const float4*)(gam + lane * 8), g1 = *(const float4*)(gam + lane * 8 + 4);
    float4 b0 = *(const float4*)(bet + lane * 8), b1 = *(const float4*)(bet + lane * 8 + 4);
    float y[8];
    y[0] = (v0.x - mean) * rstd * g0.x + b0.x;
    y[1] = (v0.y - mean) * rstd * g0.y + b0.y;
    y[2] = (v0.z - mean) * rstd * g0.z + b0.z;
    y[3] = (v0.w - mean) * rstd * g0.w + b0.w;
    y[4] = (v1.x - mean) * rstd * g1.x + b1.x;
    y[5] = (v1.y - mean) * rstd * g1.y + b1.y;
    y[6] = (v1.z - mean) * rstd * g1.z + b1.z;
    y[7] = (v1.w - mean) * rstd * g1.w + b1.w;
    bf16x8 ob;
#pragma unroll
    for (int j = 0; j < 8; ++j) ob[j] = (bf16_t)y[j];
    *(bf16x8*)(outb + (size_t)row * DMODEL + lane * 8) = ob;
    if (FINAL) {
        float4 o0 = {y[0], y[1], y[2], y[3]};
        float4 o1 = {y[4], y[5], y[6], y[7]};
        *(float4*)(outf + (size_t)row * DMODEL + lane * 8)     = o0;
        *(float4*)(outf + (size_t)row * DMODEL + lane * 8 + 4) = o1;
    }
}

// ---------------- driver ----------------
extern "C" void kernel_launch(void* const* d_in, const int* in_sizes, int n_in,
                              void* d_out, int out_size, void* d_ws, size_t ws_size,
                              hipStream_t stream)
{
    const int*   tok = (const int*)d_in[0];
    const float* emb = (const float*)d_in[1];
    const float* pos = (const float*)d_in[2];
    const float* Wk  = (const float*)d_in[3];
    const float* Wo  = (const float*)d_in[4];
    const float* W1  = (const float*)d_in[5];
    const float* b1  = (const float*)d_in[6];
    const float* W2  = (const float*)d_in[7];
    const float* b2  = (const float*)d_in[8];
    const float* gam = (const float*)d_in[9];
    const float* bet = (const float*)d_in[10];
    float* outp = (float*)d_out;

    char* ws = (char*)d_ws;
    size_t off = 0;
    auto alloc = [&](size_t bytes) {
        off = (off + 255) & ~(size_t)255;
        void* p = ws + off;
        off += bytes;
        return p;
    };
    bf16_t* WKT  = (bf16_t*)alloc((size_t)L_LAYERS * DMODEL * DMODEL * 2);
    bf16_t* WOT  = (bf16_t*)alloc((size_t)L_LAYERS * DMODEL * DMODEL * 2);
    bf16_t* W1T  = (bf16_t*)alloc((size_t)L_LAYERS * DMODEL * DFFN * 2);
    bf16_t* W2T  = (bf16_t*)alloc((size_t)L_LAYERS * DMODEL * DFFN * 2);
    bf16_t* buf0 = (bf16_t*)alloc((size_t)BN_ROWS * DMODEL * 2);
    bf16_t* buf1 = (bf16_t*)alloc((size_t)BN_ROWS * DMODEL * 2);
    bf16_t* kb   = (bf16_t*)alloc((size_t)BN_ROWS * DMODEL * 2);
    bf16_t* ob   = (bf16_t*)alloc((size_t)BN_ROWS * DMODEL * 2);
    bf16_t* h1b  = (bf16_t*)alloc((size_t)BN_ROWS * DFFN * 2);
    float*  tf   = (float*)alloc((size_t)BN_ROWS * DMODEL * 4);

    transpose_wk8<<<768, 256, 0, stream>>>(Wk, WKT);
    transpose_w8<<<768, 256, 0, stream>>>(Wo, WOT, DMODEL, DMODEL);
    transpose_w8<<<3072, 256, 0, stream>>>(W1, W1T, DMODEL, DFFN);
    transpose_w8<<<3072, 256, 0, stream>>>(W2, W2T, DFFN, DMODEL);

    embed_k<<<BN_ROWS, 128, 0, stream>>>(tok, emb, pos, buf0);

    for (int l = 0; l < L_LAYERS; ++l) {
        // k = x @ Wk   [BN,512] bf16   (150x4 = 600 tiles of 128^2, 2 blocks/CU)
        gemm128<0, bf16_t><<<600, 256, 0, stream>>>(
            buf0, WKT + (size_t)l * DMODEL * DMODEL, kb, nullptr, nullptr,
            DMODEL, DMODEL, 4);
        // attention (Q=K=V=k)
        attn_k<<<BATCH * HEADS, 256, 0, stream>>>(kb, ob);
        // t = o @ Wo + x   (f32)
        gemm128<1, float><<<600, 256, 0, stream>>>(
            ob, WOT + (size_t)l * DMODEL * DMODEL, tf, nullptr, buf0,
            DMODEL, DMODEL, 4);
        // z = LN(t)
        ln_k<false><<<BN_ROWS / 4, 256, 0, stream>>>(
            tf, gam + l * DMODEL, bet + l * DMODEL, buf1, nullptr);
        // h1 = relu(z @ W1 + b1)  bf16  (75x8 = 600 tiles of 256^2)
        gemm256<2, bf16_t><<<600, 512, 0, stream>>>(
            buf1, W1T + (size_t)l * DMODEL * DFFN, h1b, b1 + l * DFFN, nullptr,
            DMODEL, DFFN, 8);
        // t = h1 @ W2 + b2 + z   (f32)  (150x4 = 600 tiles of 128^2, K=2048)
        gemm128<3, float><<<600, 256, 0, stream>>>(
            h1b, W2T + (size_t)l * DMODEL * DFFN, tf, b2 + l * DMODEL, buf1,
            DFFN, DMODEL, 4);
        // x = LN(t)
        if (l < L_LAYERS - 1)
            ln_k<false><<<BN_ROWS / 4, 256, 0, stream>>>(
                tf, gam + l * DMODEL, bet + l * DMODEL, buf0, nullptr);
        else
            ln_k<true><<<BN_ROWS / 4, 256, 0, stream>>>(
                tf, gam + l * DMODEL, bet + l * DMODEL, buf0, outp);
    }
}

// Round 6
// 1530.170 us; speedup vs baseline: 1.1673x; 1.0238x over previous
//
#include <hip/hip_runtime.h>

// ---- problem constants ----
#define L_LAYERS 6
#define HEADS    8
#define DMODEL   512
#define DHEAD    64
#define SEQ      300
#define BATCH    64
#define DFFN     2048
#define BN_ROWS  (BATCH*SEQ)   // 19200 = 150 * 128 exactly
#define NPAD     320           // SEQ padded to 20*16

typedef __bf16 bf16_t;
typedef bf16_t bf16x8 __attribute__((ext_vector_type(8)));
typedef bf16_t bf16x4 __attribute__((ext_vector_type(4)));
typedef float  f32x4  __attribute__((ext_vector_type(4)));

// async global->LDS, 16B per lane. LDS dest must be linear in lane order.
#define GLOAD16(gp, lp) __builtin_amdgcn_global_load_lds( \
    (__attribute__((address_space(1))) void*)(gp),        \
    (__attribute__((address_space(3))) void*)(lp), 16, 0, 0)

#define MEMBAR() asm volatile("" ::: "memory")
#define PHASE_BAR() do { MEMBAR(); __builtin_amdgcn_s_barrier(); MEMBAR(); } while (0)
#define VMCNT0() asm volatile("s_waitcnt vmcnt(0)" ::: "memory")

// ---------------- weight transpose + bf16 convert ----------------
__global__ __launch_bounds__(256) void transpose_w8(const float* __restrict__ w,
                                                    bf16_t* __restrict__ o,
                                                    int K, int Nc)
{
    int idx = blockIdx.x * 256 + threadIdx.x;   // over L*K/8*Nc
    int n   = idx % Nc;
    int r   = idx / Nc;
    int k8  = (r % (K / 8)) * 8;
    int l   = r / (K / 8);
    const float* wp = w + (size_t)l * K * Nc + (size_t)k8 * Nc + n;
    bf16x8 t;
#pragma unroll
    for (int j = 0; j < 8; ++j) t[j] = (bf16_t)wp[(size_t)j * Nc];
    *(bf16x8*)(o + (size_t)l * K * Nc + (size_t)n * K + k8) = t;
}

// Wk [L][H][D][DH] f32 -> o [L][h*64+e][d] bf16
__global__ __launch_bounds__(256) void transpose_wk8(const float* __restrict__ wk,
                                                     bf16_t* __restrict__ o)
{
    int idx = blockIdx.x * 256 + threadIdx.x;
    int e  = idx % DHEAD;
    int r  = idx / DHEAD;
    int d8 = (r % (DMODEL / 8)) * 8;
    r      = r / (DMODEL / 8);
    int h  = r % HEADS;
    int l  = r / HEADS;
    const float* wp = wk + (((size_t)(l * HEADS + h) * DMODEL + d8) * DHEAD + e);
    bf16x8 t;
#pragma unroll
    for (int j = 0; j < 8; ++j) t[j] = (bf16_t)wp[(size_t)j * DHEAD];
    *(bf16x8*)(o + (size_t)l * DMODEL * DMODEL + (size_t)(h * DHEAD + e) * DMODEL + d8) = t;
}

// ---------------- embedding ----------------
__global__ __launch_bounds__(128) void embed_k(const int* __restrict__ tok,
                                               const float* __restrict__ emb,
                                               const float* __restrict__ pos,
                                               bf16_t* __restrict__ xb)
{
    int row = blockIdx.x;
    int n   = row % SEQ;
    int tkn = tok[row];
    int c   = threadIdx.x * 4;
    float4 e = *(const float4*)(emb + (size_t)tkn * DMODEL + c);
    float4 p = *(const float4*)(pos + (size_t)n * DMODEL + c);
    bf16x4 o;
    o[0] = (bf16_t)(e.x + p.x); o[1] = (bf16_t)(e.y + p.y);
    o[2] = (bf16_t)(e.z + p.z); o[3] = (bf16_t)(e.w + p.w);
    *(bf16x4*)(xb + (size_t)row * DMODEL + c) = o;
}

// ---------------- 128x128 GEMM, 64 KB LDS -> 2 blocks/CU (cross-block hiding) ----------------
// EPI: 0 none(bf16) | 1 +resid | 2 +bias,relu | 3 +bias+resid
template <int EPI, typename OUT_T>
__global__ __launch_bounds__(256, 2) void gemm128(const bf16_t* __restrict__ A,
                                                  const bf16_t* __restrict__ BT,
                                                  OUT_T* __restrict__ C,
                                                  const float* __restrict__ bias,
                                                  const bf16_t* __restrict__ resid,
                                                  int K, int Nc, int tiles_n)
{
    __shared__ bf16_t smem[32768];   // 64 KB: A[2][128][64] + B[2][128][64]
    bf16_t* As = smem;
    bf16_t* Bs = smem + 16384;

    const int t = threadIdx.x;
    const int nwg = gridDim.x;
    const int q = nwg >> 3, r = nwg & 7;
    const int xc = blockIdx.x & 7, sq = blockIdx.x >> 3;
    const int lt = (xc < r ? xc * (q + 1) : r * (q + 1) + (xc - r) * q) + sq;
    const int tm = lt / tiles_n, tn = lt % tiles_n;

    const bf16_t* Ab = A  + (size_t)tm * 128 * K;
    const bf16_t* Bb = BT + (size_t)tn * 128 * K;
    const int lane = t & 63, wid = t >> 6;
    const int wr = wid >> 1, wc = wid & 1;
    const int fr = lane & 15, fq = lane >> 4;
    const int NT = K >> 6;

    auto stage = [&](bf16_t* dst, const bf16_t* src, int kt) {
#pragma unroll
        for (int j = 0; j < 4; ++j) {
            int idx8 = (j * 256 + t) * 8;
            int rl   = idx8 >> 6;
            int cg   = (idx8 & 63) ^ ((rl & 7) << 3);
            GLOAD16(src + (size_t)rl * K + kt * 64 + cg, dst + idx8);
        }
    };

    const f32x4 FZ = {0.f, 0.f, 0.f, 0.f};
    f32x4 acc[4][4];
#pragma unroll
    for (int m = 0; m < 4; ++m)
#pragma unroll
        for (int n = 0; n < 4; ++n) acc[m][n] = FZ;

    stage(As, Ab, 0); stage(Bs, Bb, 0);
    VMCNT0(); PHASE_BAR();

    for (int tt = 0; tt < NT; ++tt) {
        const int buf = tt & 1, nbuf = buf ^ 1;
        const bf16_t* Ap = As + buf * 8192 + (wr * 64 + fr) * 64;
        const bf16_t* Bp = Bs + buf * 8192 + (wc * 64 + fr) * 64;
        const int ca0 = (fq * 8) ^ ((fr & 7) << 3);
        const int ca1 = ca0 ^ 32;
        bf16x8 af[4], bfr[4];
#pragma unroll
        for (int m = 0; m < 4; ++m) af[m] = *(const bf16x8*)(Ap + m * 1024 + ca0);
#pragma unroll
        for (int n = 0; n < 4; ++n) bfr[n] = *(const bf16x8*)(Bp + n * 1024 + ca0);
        if (tt + 1 < NT) { stage(As + nbuf * 8192, Ab, tt + 1); stage(Bs + nbuf * 8192, Bb, tt + 1); }
        __builtin_amdgcn_s_setprio(1);
#pragma unroll
        for (int m = 0; m < 4; ++m)
#pragma unroll
            for (int n = 0; n < 4; ++n)
                acc[m][n] = __builtin_amdgcn_mfma_f32_16x16x32_bf16(af[m], bfr[n], acc[m][n], 0, 0, 0);
        __builtin_amdgcn_s_setprio(0);
#pragma unroll
        for (int m = 0; m < 4; ++m) af[m] = *(const bf16x8*)(Ap + m * 1024 + ca1);
#pragma unroll
        for (int n = 0; n < 4; ++n) bfr[n] = *(const bf16x8*)(Bp + n * 1024 + ca1);
        __builtin_amdgcn_s_setprio(1);
#pragma unroll
        for (int m = 0; m < 4; ++m)
#pragma unroll
            for (int n = 0; n < 4; ++n)
                acc[m][n] = __builtin_amdgcn_mfma_f32_16x16x32_bf16(af[m], bfr[n], acc[m][n], 0, 0, 0);
        __builtin_amdgcn_s_setprio(0);
        VMCNT0(); PHASE_BAR();
    }

#pragma unroll
    for (int m = 0; m < 4; ++m) {
#pragma unroll
        for (int n = 0; n < 4; ++n) {
            int colg = tn * 128 + wc * 64 + n * 16 + fr;
            float bv = (EPI == 2 || EPI == 3) ? bias[colg] : 0.f;
#pragma unroll
            for (int rr2 = 0; rr2 < 4; ++rr2) {
                int rowg = tm * 128 + wr * 64 + m * 16 + fq * 4 + rr2;
                float v = acc[m][n][rr2] + bv;
                if (EPI == 2) v = fmaxf(v, 0.f);
                if (EPI == 1 || EPI == 3) v += (float)resid[(size_t)rowg * Nc + colg];
                C[(size_t)rowg * Nc + colg] = (OUT_T)v;
            }
        }
    }
}

// ---------------- fused attention for one (b,h); exploits Q=K=V ----------------
__global__ __launch_bounds__(256) void attn_k(const bf16_t* __restrict__ kin,
                                              bf16_t* __restrict__ out)
{
    __shared__ bf16_t Kl[NPAD * 64];
    __shared__ bf16_t KT[64 * NPAD];
    __shared__ bf16_t Pl[4 * 16 * NPAD];

    const int bh = blockIdx.x;
    const int b  = bh >> 3, h = bh & 7;
    const bf16_t* kbase = kin + (size_t)b * SEQ * DMODEL + h * DHEAD;
    const int t  = threadIdx.x;
    const int rr = t >> 3;
    const int cg = (t & 7) * 8;

    for (int pass = 0; pass < NPAD / 32; ++pass) {
        int row = pass * 32 + rr;
        bf16x8 v;
        if (row < SEQ) v = *(const bf16x8*)(kbase + (size_t)row * DMODEL + cg);
        else {
#pragma unroll
            for (int j = 0; j < 8; ++j) v[j] = (bf16_t)0.f;
        }
        *(bf16x8*)(Kl + row * 64 + (cg ^ ((row & 7) << 3))) = v;
#pragma unroll
        for (int j = 0; j < 8; ++j) {
            int col = cg + j;
            KT[col * NPAD + (row ^ ((col & 7) << 3))] = v[j];
        }
    }
    __syncthreads();

    const int lane = t & 63, w = t >> 6;
    const int fr = lane & 15, fq = lane >> 4;
    const float scale = 0.044194173824159216f;   // 1/sqrt(512)
    const f32x4 FZ = {0.f, 0.f, 0.f, 0.f};

    for (int i = 0; i < 5; ++i) {
        int qt = w * 5 + i;
        f32x4 s[20];
#pragma unroll
        for (int ct = 0; ct < 20; ++ct) s[ct] = FZ;
#pragma unroll
        for (int kk = 0; kk < 2; ++kk) {
            int qrow = qt * 16 + fr;
            bf16x8 aq = *(const bf16x8*)(Kl + qrow * 64 + ((kk * 32 + fq * 8) ^ ((qrow & 7) << 3)));
#pragma unroll
            for (int ct = 0; ct < 20; ++ct) {
                int krow = ct * 16 + fr;
                bf16x8 bk = *(const bf16x8*)(Kl + krow * 64 + ((kk * 32 + fq * 8) ^ ((krow & 7) << 3)));
                s[ct] = __builtin_amdgcn_mfma_f32_16x16x32_bf16(aq, bk, s[ct], 0, 0, 0);
            }
        }
#pragma unroll
        for (int r = 0; r < 4; ++r) {
            float mx = -1e30f;
#pragma unroll
            for (int ct = 0; ct < 20; ++ct) {
                float v = s[ct][r] * scale;
                if (ct * 16 + fr < SEQ) mx = fmaxf(mx, v);
            }
            mx = fmaxf(mx, __shfl_xor(mx, 1));
            mx = fmaxf(mx, __shfl_xor(mx, 2));
            mx = fmaxf(mx, __shfl_xor(mx, 4));
            mx = fmaxf(mx, __shfl_xor(mx, 8));
            float p[20];
            float sm = 0.f;
#pragma unroll
            for (int ct = 0; ct < 20; ++ct) {
                float v = (ct * 16 + fr < SEQ) ? __expf(s[ct][r] * scale - mx) : 0.f;
                p[ct] = v; sm += v;
            }
            sm += __shfl_xor(sm, 1); sm += __shfl_xor(sm, 2);
            sm += __shfl_xor(sm, 4); sm += __shfl_xor(sm, 8);
            float rinv = 1.f / sm;
            int pr = fq * 4 + r;
#pragma unroll
            for (int ct = 0; ct < 20; ++ct) {
                int col = ct * 16 + fr;
                Pl[(w * 16 + pr) * NPAD + (col ^ ((pr & 7) << 3))] = (bf16_t)(p[ct] * rinv);
            }
        }
#pragma unroll
        for (int n = 0; n < 4; ++n) {
            f32x4 oacc = FZ;
#pragma unroll
            for (int kk = 0; kk < 10; ++kk) {
                bf16x8 ap = *(const bf16x8*)(Pl + (w * 16 + fr) * NPAD + ((kk * 32 + fq * 8) ^ ((fr & 7) << 3)));
                int dr = n * 16 + fr;
                bf16x8 bv = *(const bf16x8*)(KT + dr * NPAD + ((kk * 32 + fq * 8) ^ ((dr & 7) << 3)));
                oacc = __builtin_amdgcn_mfma_f32_16x16x32_bf16(ap, bv, oacc, 0, 0, 0);
            }
#pragma unroll
            for (int r = 0; r < 4; ++r) {
                int qrow = qt * 16 + fq * 4 + r;
                if (qrow < SEQ)
                    out[(size_t)(b * SEQ + qrow) * DMODEL + h * DHEAD + n * 16 + fr] = (bf16_t)oacc[r];
            }
        }
    }
}

// ---------------- layernorm (bf16 in): one wave per row of 512 ----------------
template <bool FINAL>
__global__ __launch_bounds__(256) void ln_k(const bf16_t* __restrict__ in,
                                            const float* __restrict__ gam,
                                            const float* __restrict__ bet,
                                            bf16_t* __restrict__ outb,
                                            float* __restrict__ outf)
{
    int row  = blockIdx.x * 4 + (threadIdx.x >> 6);
    int lane = threadIdx.x & 63;
    bf16x8 v = *(const bf16x8*)(in + (size_t)row * DMODEL + lane * 8);
    float y[8];
    float s = 0.f, s2 = 0.f;
#pragma unroll
    for (int j = 0; j < 8; ++j) {
        float f = (float)v[j];
        y[j] = f; s += f; s2 += f * f;
    }
#pragma unroll
    for (int m = 1; m < 64; m <<= 1) { s += __shfl_xor(s, m); s2 += __shfl_xor(s2, m); }
    float mean = s * (1.f / DMODEL);
    float rstd = rsqrtf(s2 * (1.f / DMODEL) - mean * mean + 1e-5f);
    float4 g0 = *(const float4*)(gam + lane * 8), g1 = *(const float4*)(gam + lane * 8 + 4);
    float4 b0 = *(const float4*)(bet + lane * 8), b1 = *(const float4*)(bet + lane * 8 + 4);
    float z[8];
    z[0] = (y[0] - mean) * rstd * g0.x + b0.x;
    z[1] = (y[1] - mean) * rstd * g0.y + b0.y;
    z[2] = (y[2] - mean) * rstd * g0.z + b0.z;
    z[3] = (y[3] - mean) * rstd * g0.w + b0.w;
    z[4] = (y[4] - mean) * rstd * g1.x + b1.x;
    z[5] = (y[5] - mean) * rstd * g1.y + b1.y;
    z[6] = (y[6] - mean) * rstd * g1.z + b1.z;
    z[7] = (y[7] - mean) * rstd * g1.w + b1.w;
    bf16x8 ob;
#pragma unroll
    for (int j = 0; j < 8; ++j) ob[j] = (bf16_t)z[j];
    *(bf16x8*)(outb + (size_t)row * DMODEL + lane * 8) = ob;
    if (FINAL) {
        float4 o0 = {z[0], z[1], z[2], z[3]};
        float4 o1 = {z[4], z[5], z[6], z[7]};
        *(float4*)(outf + (size_t)row * DMODEL + lane * 8)     = o0;
        *(float4*)(outf + (size_t)row * DMODEL + lane * 8 + 4) = o1;
    }
}

// ---------------- driver ----------------
extern "C" void kernel_launch(void* const* d_in, const int* in_sizes, int n_in,
                              void* d_out, int out_size, void* d_ws, size_t ws_size,
                              hipStream_t stream)
{
    const int*   tok = (const int*)d_in[0];
    const float* emb = (const float*)d_in[1];
    const float* pos = (const float*)d_in[2];
    const float* Wk  = (const float*)d_in[3];
    const float* Wo  = (const float*)d_in[4];
    const float* W1  = (const float*)d_in[5];
    const float* b1  = (const float*)d_in[6];
    const float* W2  = (const float*)d_in[7];
    const float* b2  = (const float*)d_in[8];
    const float* gam = (const float*)d_in[9];
    const float* bet = (const float*)d_in[10];
    float* outp = (float*)d_out;

    char* ws = (char*)d_ws;
    size_t off = 0;
    auto alloc = [&](size_t bytes) {
        off = (off + 255) & ~(size_t)255;
        void* p = ws + off;
        off += bytes;
        return p;
    };
    bf16_t* WKT  = (bf16_t*)alloc((size_t)L_LAYERS * DMODEL * DMODEL * 2);
    bf16_t* WOT  = (bf16_t*)alloc((size_t)L_LAYERS * DMODEL * DMODEL * 2);
    bf16_t* W1T  = (bf16_t*)alloc((size_t)L_LAYERS * DMODEL * DFFN * 2);
    bf16_t* W2T  = (bf16_t*)alloc((size_t)L_LAYERS * DMODEL * DFFN * 2);
    bf16_t* buf0 = (bf16_t*)alloc((size_t)BN_ROWS * DMODEL * 2);   // x
    bf16_t* buf1 = (bf16_t*)alloc((size_t)BN_ROWS * DMODEL * 2);   // z
    bf16_t* kb   = (bf16_t*)alloc((size_t)BN_ROWS * DMODEL * 2);   // k = q = v
    bf16_t* ob   = (bf16_t*)alloc((size_t)BN_ROWS * DMODEL * 2);   // attn out
    bf16_t* h1b  = (bf16_t*)alloc((size_t)BN_ROWS * DFFN * 2);     // ffn hidden
    bf16_t* tfb  = (bf16_t*)alloc((size_t)BN_ROWS * DMODEL * 2);   // pre-LN t (bf16)

    transpose_wk8<<<768, 256, 0, stream>>>(Wk, WKT);
    transpose_w8<<<768, 256, 0, stream>>>(Wo, WOT, DMODEL, DMODEL);
    transpose_w8<<<3072, 256, 0, stream>>>(W1, W1T, DMODEL, DFFN);
    transpose_w8<<<3072, 256, 0, stream>>>(W2, W2T, DFFN, DMODEL);

    embed_k<<<BN_ROWS, 128, 0, stream>>>(tok, emb, pos, buf0);

    for (int l = 0; l < L_LAYERS; ++l) {
        // k = x @ Wk   [BN,512] bf16
        gemm128<0, bf16_t><<<600, 256, 0, stream>>>(
            buf0, WKT + (size_t)l * DMODEL * DMODEL, kb, nullptr, nullptr,
            DMODEL, DMODEL, 4);
        // attention (Q=K=V=k)
        attn_k<<<BATCH * HEADS, 256, 0, stream>>>(kb, ob);
        // t = o @ Wo + x   (bf16)
        gemm128<1, bf16_t><<<600, 256, 0, stream>>>(
            ob, WOT + (size_t)l * DMODEL * DMODEL, tfb, nullptr, buf0,
            DMODEL, DMODEL, 4);
        // z = LN(t)
        ln_k<false><<<BN_ROWS / 4, 256, 0, stream>>>(
            tfb, gam + l * DMODEL, bet + l * DMODEL, buf1, nullptr);
        // h1 = relu(z @ W1 + b1)  bf16  (150x16 = 2400 tiles of 128^2, 2 blocks/CU)
        gemm128<2, bf16_t><<<2400, 256, 0, stream>>>(
            buf1, W1T + (size_t)l * DMODEL * DFFN, h1b, b1 + l * DFFN, nullptr,
            DMODEL, DFFN, 16);
        // t = h1 @ W2 + b2 + z   (bf16, K=2048)
        gemm128<3, bf16_t><<<600, 256, 0, stream>>>(
            h1b, W2T + (size_t)l * DMODEL * DFFN, tfb, b2 + l * DMODEL, buf1,
            DFFN, DMODEL, 4);
        // x = LN(t)
        if (l < L_LAYERS - 1)
            ln_k<false><<<BN_ROWS / 4, 256, 0, stream>>>(
                tfb, gam + l * DMODEL, bet + l * DMODEL, buf0, nullptr);
        else
            ln_k<true><<<BN_ROWS / 4, 256, 0, stream>>>(
                tfb, gam + l * DMODEL, bet + l * DMODEL, buf0, outp);
    }
}